// Round 1
// baseline (259.817 us; speedup 1.0000x reference)
//
#include <hip/hip_runtime.h>

// LocalPathEncoderRobustAdvancedTemporal — fused single kernel.
// Key identity: out[b,l,:] = (Σ_f relu(x_f*W1 + b1)) @ W2 + 8*b2
//   → collapse 8 features into g[128] per (b,l) BEFORE the matmul (8x fewer FLOPs).
// One block per sample b (256 thr). 128 rows per block = [src 0..63 | dst 64..127].
// Feature stats O(L^2) in LDS, g + W2^T staged as bf16, MFMA 16x16x32 GEMM,
// direct fp32 stores to d_out. No workspace used.

#define EPSF 1e-6f
#define LDA 136              // bf16 row pitch (128 + 8 pad: breaks 256B bank alias)

typedef __attribute__((ext_vector_type(8))) short bf16x8;
typedef __attribute__((ext_vector_type(4))) float f32x4;

__device__ inline short f2bf(float x) {           // fp32 -> bf16 (RNE)
    unsigned u = __float_as_uint(x);
    unsigned r = (u + 0x7fffu + ((u >> 16) & 1u)) >> 16;
    return (short)r;
}

__launch_bounds__(256, 2)
__global__ void lpe_kernel(const int* __restrict__ src_ids,
                           const int* __restrict__ dst_ids,
                           const int* __restrict__ src_nid,
                           const int* __restrict__ dst_nid,
                           const float* __restrict__ t_now,
                           const float* __restrict__ src_t,
                           const float* __restrict__ dst_t,
                           const float* __restrict__ W1,
                           const float* __restrict__ b1,
                           const float* __restrict__ W2,
                           const float* __restrict__ b2,
                           float* __restrict__ out)
{
    __shared__ int   s_ids[128];
    __shared__ float s_t[128];
    __shared__ int   s_n[128];
    __shared__ int   s_rank[128];
    __shared__ float s_tmax[128];
    __shared__ float s_avg[128];
    __shared__ float s_rec[128];
    __shared__ float s_feats[128][8];
    __shared__ float s_w1[128];
    __shared__ float s_b1[128];
    __shared__ short A_lds[128 * LDA];   // g (bf16), row-major [row][k]
    __shared__ short B_lds[128 * LDA];   // W2^T (bf16): B_lds[n][k] = W2[k][n]

    const int b   = blockIdx.x;
    const int tid = threadIdx.x;

    // ---- stage W2^T -> LDS (bf16); coalesced over n ----
    for (int idx = tid; idx < 128 * 128; idx += 256) {
        int k = idx >> 7, n = idx & 127;
        B_lds[n * LDA + k] = f2bf(W2[k * 128 + n]);
    }

    // ---- load per-sample ids/times + w1/b1 ----
    if (tid < 128) {
        int side = tid >> 6, i = tid & 63;
        const int*   idp = side ? dst_ids : src_ids;
        const float* tp  = side ? dst_t   : src_t;
        s_ids[tid] = idp[b * 64 + i];
        s_t[tid]   = tp[b * 64 + i];
        s_w1[tid]  = W1[tid];
        s_b1[tid]  = b1[tid];
    }
    __syncthreads();

    // ---- group stats: n, tmax, tmin, rank ----
    if (tid < 128) {
        const int base = tid & 64;          // own-side base (0 or 64)
        const int i    = tid & 63;
        const int   my_id = s_ids[tid];
        const float my_t  = s_t[tid];
        int n = 0, rank = 0;
        float tmax = -3.4e38f, tmin = 3.4e38f;
        for (int j = 0; j < 64; ++j) {
            int   idj = s_ids[base + j];
            float tj  = s_t[base + j];
            if (idj == my_id) {
                ++n;
                tmax = fmaxf(tmax, tj);
                tmin = fminf(tmin, tj);
                if (tj < my_t || (tj == my_t && j < i)) ++rank;
            }
        }
        s_n[tid] = n; s_rank[tid] = rank; s_tmax[tid] = tmax;
        float avg = (n > 1) ? (tmax - tmin) / (float)(n - 1) : 0.f;
        s_avg[tid] = (my_id != 0) ? avg : 0.f;
    }
    __syncthreads();

    // ---- recent_iat: needs rank[] of whole side ----
    if (tid < 128) {
        const int base  = tid & 64;
        const int my_id = s_ids[tid];
        const int n     = s_n[tid];
        const int split = n >> 1;
        float tsplit = 0.f;
        for (int j = 0; j < 64; ++j) {
            if (s_ids[base + j] == my_id && s_rank[base + j] == split)
                tsplit = s_t[base + j];
        }
        float denom = fmaxf((float)(n - split - 1), 1.f);
        float rec   = (n >= 4) ? (s_tmax[tid] - tsplit) / denom : 0.f;
        s_rec[tid]  = (my_id != 0) ? rec : 0.f;
    }
    __syncthreads();

    // ---- cross features (8 per position) ----
    if (tid < 128) {
        const int side  = tid >> 6;
        const int obase = 64 - (tid & 64);  // other-side base
        const int   my_id = s_ids[tid];
        const float my_t  = s_t[tid];
        const float cur   = t_now[b];
        const int other_node = side ? src_nid[b] : dst_nid[b];

        int c_other = 0, last_idx = -1, first_idx = -1;
        for (int j = 0; j < 64; ++j) {
            int idj = s_ids[obase + j];
            if (idj == my_id) {
                ++c_other;
                if (idj != 0) { last_idx = j; if (first_idx < 0) first_idx = j; }
            }
        }
        float c_self = (float)s_n[tid];
        float co     = (float)c_other;
        float f_is   = (my_id == other_node) ? 1.f : 0.f;
        float f_conn = (c_other > 0) ? 1.f : 0.f;
        float f_freq = (c_other > 0) ? c_self / (co + EPSF) : 0.f;
        float last_t = (last_idx >= 0) ? s_t[obase + last_idx] : 0.f;
        float rcy_s  = cur - my_t;
        float rcy_o  = cur - last_t;
        float f_temp = (rcy_s > EPSF) ? rcy_o / (rcy_s + EPSF) : 0.f;
        float iat_o  = (first_idx >= 0) ? s_avg[obase + first_idx] : 0.f;
        float f_iat  = (iat_o > EPSF) ? s_avg[tid] / (iat_o + EPSF) : 0.f;
        float riat_o = (first_idx >= 0) ? s_rec[obase + first_idx] : 0.f;
        float f_riat = (riat_o > EPSF) ? s_rec[tid] / (riat_o + EPSF) : 0.f;
        float m = (my_id != 0) ? 1.f : 0.f;   // feature row mask (id==0)
        s_feats[tid][0] = m * c_self;
        s_feats[tid][1] = m * co;
        s_feats[tid][2] = m * f_is;
        s_feats[tid][3] = m * f_conn;
        s_feats[tid][4] = m * f_freq;
        s_feats[tid][5] = m * f_temp;
        s_feats[tid][6] = m * f_iat;
        s_feats[tid][7] = m * f_riat;
    }
    __syncthreads();

    // ---- g[row][d] = sum_f relu(w1[d]*x_f + b1[d])  -> bf16 LDS ----
    for (int idx = tid; idx < 128 * 128; idx += 256) {
        int row = idx >> 7, d = idx & 127;   // d constant per thread (stride 256)
        float w = s_w1[d], bb = s_b1[d];
        float g = 0.f;
        #pragma unroll
        for (int f = 0; f < 8; ++f) {
            float v = fmaf(s_feats[row][f], w, bb);
            g += fmaxf(v, 0.f);
        }
        A_lds[row * LDA + d] = f2bf(g);
    }
    __syncthreads();

    // ---- GEMM: [128 x 128] = g @ W2, mfma 16x16x32 bf16 ----
    // wave w owns M-tiles {2w, 2w+1} x all 8 N-tiles.
    const int lane = tid & 63;
    const int wv   = tid >> 6;
    const int quad = lane >> 4;
    const int ln   = lane & 15;

    f32x4 acc[2][8];
    #pragma unroll
    for (int mi = 0; mi < 2; ++mi)
        #pragma unroll
        for (int nt = 0; nt < 8; ++nt)
            acc[mi][nt] = (f32x4){0.f, 0.f, 0.f, 0.f};

    #pragma unroll
    for (int kk = 0; kk < 4; ++kk) {
        const int kof = kk * 32 + quad * 8;
        bf16x8 a0 = *(const bf16x8*)&A_lds[(wv * 32 + ln)      * LDA + kof];
        bf16x8 a1 = *(const bf16x8*)&A_lds[(wv * 32 + 16 + ln) * LDA + kof];
        #pragma unroll
        for (int nt = 0; nt < 8; ++nt) {
            bf16x8 bf = *(const bf16x8*)&B_lds[(nt * 16 + ln) * LDA + kof];
            acc[0][nt] = __builtin_amdgcn_mfma_f32_16x16x32_bf16(a0, bf, acc[0][nt], 0, 0, 0);
            acc[1][nt] = __builtin_amdgcn_mfma_f32_16x16x32_bf16(a1, bf, acc[1][nt], 0, 0, 0);
        }
    }

    // ---- epilogue: out[row][e] += 8*b2[e]; rows 0..63 -> src, 64..127 -> dst ----
    const long side_stride = 2048L * 64L * 128L;
    #pragma unroll
    for (int mi = 0; mi < 2; ++mi) {
        const int row0 = wv * 32 + mi * 16 + quad * 4;
        #pragma unroll
        for (int nt = 0; nt < 8; ++nt) {
            const int e = nt * 16 + ln;
            const float badd = 8.f * b2[e];
            #pragma unroll
            for (int r = 0; r < 4; ++r) {
                const int rr   = row0 + r;
                const int side = rr >> 6;
                const int i    = rr & 63;
                out[(long)side * side_stride + ((long)(b * 64 + i)) * 128 + e]
                    = acc[mi][nt][r] + badd;
            }
        }
    }
}

extern "C" void kernel_launch(void* const* d_in, const int* in_sizes, int n_in,
                              void* d_out, int out_size, void* d_ws, size_t ws_size,
                              hipStream_t stream) {
    (void)in_sizes; (void)n_in; (void)out_size; (void)d_ws; (void)ws_size;
    const int*   src_ids = (const int*)  d_in[0];
    const int*   dst_ids = (const int*)  d_in[1];
    const int*   src_nid = (const int*)  d_in[2];
    const int*   dst_nid = (const int*)  d_in[3];
    const float* t_now   = (const float*)d_in[4];
    const float* src_t   = (const float*)d_in[5];
    const float* dst_t   = (const float*)d_in[6];
    const float* W1      = (const float*)d_in[7];
    const float* b1      = (const float*)d_in[8];
    const float* W2      = (const float*)d_in[9];
    const float* b2      = (const float*)d_in[10];
    lpe_kernel<<<2048, 256, 0, stream>>>(src_ids, dst_ids, src_nid, dst_nid,
                                         t_now, src_t, dst_t, W1, b1, W2, b2,
                                         (float*)d_out);
}

// Round 2
// 214.178 us; speedup vs baseline: 1.2131x; 1.2131x over previous
//
#include <hip/hip_runtime.h>

// LocalPathEncoderRobustAdvancedTemporal — fused, register-resident g, swapped MFMA.
// out[b,l,:] = (Σ_f relu(x_f*W1 + b1)) @ W2 + 8*b2   (8x FLOP collapse, exact)
// R1 changes vs R0:
//  * MFMA operands swapped: A=W2^T rows (m=e), B=g rows (n=row) → lane owns 4
//    consecutive e per row → float4 coalesced stores (4x fewer store instrs).
//  * g fragments computed straight into VGPRs (no A_lds round trip).
//  * W2^T bf16 precomputed once in d_ws by a prep kernel; staged to LDS with
//    conflict-free b128 copies, overlapped with the stats loops (waves 2-3).
//  * LDS 78KB -> 43.5KB => 3 blocks/CU; stats read packed (id,t) int2.

#define EPSF 1e-6f
#define LDB 136              // W2T LDS row pitch in shorts (128+8: b128 reads 2-way only)

typedef __attribute__((ext_vector_type(8))) short bf16x8;
typedef __attribute__((ext_vector_type(4))) float f32x4;

__device__ inline short f2bf(float x) {           // fp32 -> bf16 (RNE)
    unsigned u = __float_as_uint(x);
    unsigned r = (u + 0x7fffu + ((u >> 16) & 1u)) >> 16;
    return (short)r;
}

__global__ void w2t_prep(const float* __restrict__ W2, short* __restrict__ w2t) {
    const int idx = blockIdx.x * 256 + threadIdx.x;   // 16384 elems
    const int n = idx >> 7, k = idx & 127;
    w2t[n * 128 + k] = f2bf(W2[k * 128 + n]);
}

template <bool FROMWS>
__launch_bounds__(256, 3)
__global__ void lpe_main(const int* __restrict__ src_ids,
                         const int* __restrict__ dst_ids,
                         const int* __restrict__ src_nid,
                         const int* __restrict__ dst_nid,
                         const float* __restrict__ t_now,
                         const float* __restrict__ src_t,
                         const float* __restrict__ dst_t,
                         const float* __restrict__ W1,
                         const float* __restrict__ b1,
                         const float* __restrict__ W2,
                         const float* __restrict__ b2,
                         const short* __restrict__ w2t,
                         float* __restrict__ out)
{
    __shared__ short W2T[128 * LDB];      // 34816 B
    __shared__ int2  s_idt[128];          // {id, t bits}
    __shared__ int   s_n[128];
    __shared__ int   s_rank[128];
    __shared__ float s_avg[128];
    __shared__ float s_rec[128];
    __shared__ float s_feats[128][8];
    __shared__ float s_w1[128];
    __shared__ float s_b1[128];

    const int b   = blockIdx.x;
    const int tid = threadIdx.x;

    // persistent per-thread stats registers (tid<128 lanes)
    int   my_id = 0;  float my_t = 0.f;
    int   n_g = 0;    float tmax_g = 0.f;
    float avg_m = 0.f, rec_m = 0.f;

    // ---- seg0: load ids/times/params (waves 0-1) | stage W2T half 1 (waves 2-3) ----
    if (tid < 128) {
        const int side = tid >> 6, i = tid & 63;
        const int*   idp = side ? dst_ids : src_ids;
        const float* tp  = side ? dst_t   : src_t;
        my_id = idp[b * 64 + i];
        my_t  = tp[b * 64 + i];
        s_idt[tid] = make_int2(my_id, __float_as_int(my_t));
        s_w1[tid]  = W1[tid];
        s_b1[tid]  = b1[tid];
    } else {
        const int t2 = tid - 128;
        if constexpr (FROMWS) {
            for (int u = t2; u < 1024; u += 128) {
                const int n = u >> 4, ku = (u & 15) << 3;
                *(bf16x8*)&W2T[n * LDB + ku] = *(const bf16x8*)&w2t[n * 128 + ku];
            }
        } else {
            for (int u = t2; u < 8192; u += 128) {
                const int k = u >> 7, n = u & 127;
                W2T[n * LDB + k] = f2bf(W2[k * 128 + n]);
            }
        }
    }
    __syncthreads();

    // ---- seg1: group stats loop (waves 0-1) | stage W2T half 2 (waves 2-3) ----
    if (tid < 128) {
        const int base = tid & 64, i = tid & 63;
        int n = 0, rank = 0;
        float tmax = -3.4e38f, tmin = 3.4e38f;
        for (int j = 0; j < 64; ++j) {
            const int2 e = s_idt[base + j];
            const float tj = __int_as_float(e.y);
            if (e.x == my_id) {
                ++n;
                tmax = fmaxf(tmax, tj);
                tmin = fminf(tmin, tj);
                if (tj < my_t || (tj == my_t && j < i)) ++rank;
            }
        }
        n_g = n; tmax_g = tmax;
        s_n[tid] = n; s_rank[tid] = rank;
        const float avg = (n > 1) ? (tmax - tmin) / (float)(n - 1) : 0.f;
        avg_m = (my_id != 0) ? avg : 0.f;
        s_avg[tid] = avg_m;
    } else {
        const int t2 = tid - 128;
        if constexpr (FROMWS) {
            for (int u = t2 + 1024; u < 2048; u += 128) {
                const int n = u >> 4, ku = (u & 15) << 3;
                *(bf16x8*)&W2T[n * LDB + ku] = *(const bf16x8*)&w2t[n * 128 + ku];
            }
        } else {
            for (int u = t2 + 8192; u < 16384; u += 128) {
                const int k = u >> 7, n = u & 127;
                W2T[n * LDB + k] = f2bf(W2[k * 128 + n]);
            }
        }
    }
    __syncthreads();

    // ---- seg2: recent_iat (needs all ranks) ----
    if (tid < 128) {
        const int base = tid & 64;
        const int split = n_g >> 1;
        float tsplit = 0.f;
        for (int j = 0; j < 64; ++j) {
            const int2 e = s_idt[base + j];
            if (e.x == my_id && s_rank[base + j] == split)
                tsplit = __int_as_float(e.y);
        }
        const float denom = fmaxf((float)(n_g - split - 1), 1.f);
        const float rec = (n_g >= 4) ? (tmax_g - tsplit) / denom : 0.f;
        rec_m = (my_id != 0) ? rec : 0.f;
        s_rec[tid] = rec_m;
    }
    __syncthreads();

    // ---- seg3: cross features (needs other side's avg/rec) ----
    if (tid < 128) {
        const int side  = tid >> 6;
        const int obase = 64 - (tid & 64);
        const float cur = t_now[b];
        const int other_node = side ? src_nid[b] : dst_nid[b];

        int c_other = 0, first_idx = -1;
        float last_t = 0.f;
        for (int j = 0; j < 64; ++j) {
            const int2 e = s_idt[obase + j];
            if (e.x == my_id) {
                ++c_other;
                if (e.x != 0) {
                    last_t = __int_as_float(e.y);
                    if (first_idx < 0) first_idx = j;
                }
            }
        }
        const float c_self = (float)n_g;
        const float co     = (float)c_other;
        const float f_is   = (my_id == other_node) ? 1.f : 0.f;
        const float f_conn = (c_other > 0) ? 1.f : 0.f;
        const float f_freq = (c_other > 0) ? c_self / (co + EPSF) : 0.f;
        const float rcy_s  = cur - my_t;
        const float rcy_o  = cur - last_t;
        const float f_temp = (rcy_s > EPSF) ? rcy_o / (rcy_s + EPSF) : 0.f;
        const float iat_o  = (first_idx >= 0) ? s_avg[obase + first_idx] : 0.f;
        const float f_iat  = (iat_o > EPSF) ? avg_m / (iat_o + EPSF) : 0.f;
        const float riat_o = (first_idx >= 0) ? s_rec[obase + first_idx] : 0.f;
        const float f_riat = (riat_o > EPSF) ? rec_m / (riat_o + EPSF) : 0.f;
        const float m = (my_id != 0) ? 1.f : 0.f;
        s_feats[tid][0] = m * c_self;
        s_feats[tid][1] = m * co;
        s_feats[tid][2] = m * f_is;
        s_feats[tid][3] = m * f_conn;
        s_feats[tid][4] = m * f_freq;
        s_feats[tid][5] = m * f_temp;
        s_feats[tid][6] = m * f_iat;
        s_feats[tid][7] = m * f_riat;
    }
    __syncthreads();

    // ---- seg4: GEMM. C^T form: acc = mfma(A=W2T rows (m=e), B=g rows (n=row)).
    // Wave wv owns rows wv*32..wv*32+31 (mi=0,1 row-tiles), all 8 e-tiles.
    const int lane = tid & 63, wv = tid >> 6;
    const int quad = lane >> 4, ln = lane & 15;

    f32x4 fx[2][2];                      // feats for my 2 rows
    #pragma unroll
    for (int mi = 0; mi < 2; ++mi) {
        const int row = wv * 32 + mi * 16 + ln;
        fx[mi][0] = *(const f32x4*)&s_feats[row][0];
        fx[mi][1] = *(const f32x4*)&s_feats[row][4];
    }

    f32x4 acc[2][8];
    #pragma unroll
    for (int mi = 0; mi < 2; ++mi)
        #pragma unroll
        for (int et = 0; et < 8; ++et)
            acc[mi][et] = (f32x4){0.f, 0.f, 0.f, 0.f};

    #pragma unroll
    for (int kk = 0; kk < 4; ++kk) {
        const int kof = kk * 32 + quad * 8;            // my 8-wide k slice
        const f32x4 w1a = *(const f32x4*)&s_w1[kof];
        const f32x4 w1b = *(const f32x4*)&s_w1[kof + 4];
        const f32x4 b1a = *(const f32x4*)&s_b1[kof];
        const f32x4 b1b = *(const f32x4*)&s_b1[kof + 4];
        bf16x8 gf[2];
        #pragma unroll
        for (int mi = 0; mi < 2; ++mi) {
            const f32x4 xa = fx[mi][0], xb = fx[mi][1];
            #pragma unroll
            for (int j = 0; j < 8; ++j) {
                const float w  = (j < 4) ? w1a[j] : w1b[j - 4];
                const float bb = (j < 4) ? b1a[j] : b1b[j - 4];
                float s = fmaxf(fmaf(xa[0], w, bb), 0.f);
                s += fmaxf(fmaf(xa[1], w, bb), 0.f);
                s += fmaxf(fmaf(xa[2], w, bb), 0.f);
                s += fmaxf(fmaf(xa[3], w, bb), 0.f);
                s += fmaxf(fmaf(xb[0], w, bb), 0.f);
                s += fmaxf(fmaf(xb[1], w, bb), 0.f);
                s += fmaxf(fmaf(xb[2], w, bb), 0.f);
                s += fmaxf(fmaf(xb[3], w, bb), 0.f);
                gf[mi][j] = f2bf(s);
            }
        }
        #pragma unroll
        for (int et = 0; et < 8; ++et) {
            const bf16x8 af = *(const bf16x8*)&W2T[(et * 16 + ln) * LDB + kof];
            acc[0][et] = __builtin_amdgcn_mfma_f32_16x16x32_bf16(af, gf[0], acc[0][et], 0, 0, 0);
            acc[1][et] = __builtin_amdgcn_mfma_f32_16x16x32_bf16(af, gf[1], acc[1][et], 0, 0, 0);
        }
    }

    // ---- epilogue: lane holds out[row][e0..e0+3] → float4 stores ----
    const long side_stride = 2048L * 64L * 128L;
    #pragma unroll
    for (int et = 0; et < 8; ++et) {
        const int e0 = et * 16 + quad * 4;
        const f32x4 bb4 = *(const f32x4*)&b2[e0];
        const f32x4 badd = bb4 * 8.f;
        #pragma unroll
        for (int mi = 0; mi < 2; ++mi) {
            const int row  = wv * 32 + mi * 16 + ln;
            const int side = row >> 6, i = row & 63;
            float* po = out + (long)side * side_stride + ((long)(b * 64 + i)) * 128 + e0;
            *(f32x4*)po = acc[mi][et] + badd;
        }
    }
}

extern "C" void kernel_launch(void* const* d_in, const int* in_sizes, int n_in,
                              void* d_out, int out_size, void* d_ws, size_t ws_size,
                              hipStream_t stream) {
    (void)in_sizes; (void)n_in; (void)out_size;
    const int*   src_ids = (const int*)  d_in[0];
    const int*   dst_ids = (const int*)  d_in[1];
    const int*   src_nid = (const int*)  d_in[2];
    const int*   dst_nid = (const int*)  d_in[3];
    const float* t_now   = (const float*)d_in[4];
    const float* src_t   = (const float*)d_in[5];
    const float* dst_t   = (const float*)d_in[6];
    const float* W1      = (const float*)d_in[7];
    const float* b1      = (const float*)d_in[8];
    const float* W2      = (const float*)d_in[9];
    const float* b2      = (const float*)d_in[10];
    float* out = (float*)d_out;

    if (ws_size >= (size_t)(128 * 128 * 2)) {
        short* w2t = (short*)d_ws;
        w2t_prep<<<64, 256, 0, stream>>>(W2, w2t);
        lpe_main<true><<<2048, 256, 0, stream>>>(src_ids, dst_ids, src_nid, dst_nid,
                                                 t_now, src_t, dst_t, W1, b1, W2, b2,
                                                 w2t, out);
    } else {
        lpe_main<false><<<2048, 256, 0, stream>>>(src_ids, dst_ids, src_nid, dst_nid,
                                                  t_now, src_t, dst_t, W1, b1, W2, b2,
                                                  nullptr, out);
    }
}